// Round 6
// baseline (108.472 us; speedup 1.0000x reference)
//
#include <hip/hip_runtime.h>
#include <math.h>

#define HH 2048
#define WW 2048
#define TILE_H 8
#define TILE_W 64
#define ROWS 10       // TILE_H + 2 halo rows
#define QC   17       // quad-columns staged (68 cols; 0..65 used)
#define LSTRIDE 68    // floats per LDS row (272 B, quad-aligned, rotates banks by 4/row)
#define GRIDX 32      // 2048 / TILE_W
#define GRIDY 256     // 2048 / TILE_H
#define NBLOCKS (GRIDX * GRIDY)   // 8192 blocks; 8/CU resident -> 4 generations
#define NITEMS (ROWS * QC)        // 170 quad-slots per tile (single load set)

// v_rcp_f32: ~1 ulp relative error — absmax threshold is 0.28, so free.
__device__ __forceinline__ float rcpf(float x) { return __builtin_amdgcn_rcpf(x); }

// Partials in d_ws: [0..8191]=sum|fx/Ec|, [8192..16383]=sum|fy/Ec|, [16384..24575]=sumE
__global__ __launch_bounds__(256, 8) void fused_loss_kernel(
    const float* __restrict__ pred_E,
    const float* __restrict__ pred_v,
    const float* __restrict__ strain,
    float* __restrict__ part)
{
    __shared__ float sE [ROWS][LSTRIDE];
    __shared__ float sxx[ROWS][LSTRIDE];
    __shared__ float syy[ROWS][LSTRIDE];
    __shared__ float sxy[ROWS][LSTRIDE];
    __shared__ float red[3][4];

    const int tid = threadIdx.x;
    const int r0 = blockIdx.y * TILE_H;
    const int c0 = blockIdx.x * TILE_W;

    float sumE = 0.f, ax = 0.f, ay = 0.f;

    // ---- stage: single set of 5 dwordx4 per active thread (tid < 170) ----
    const int r = tid / QC;
    const int q = tid - r * QC;
    const int gi = r0 + r;
    const int gc = c0 + q * 4;
    const bool ld = (tid < NITEMS) && (gi < HH) && (gc < WW);
    if (ld) {
        const int g = gi * WW + gc;
        const float4 E = *(const float4*)(pred_E + g);
        const float4 V = *(const float4*)(pred_v + g);
        const float* sp = strain + 3 * g;
        const float4 A = *(const float4*)(sp);
        const float4 B = *(const float4*)(sp + 4);
        const float4 C = *(const float4*)(sp + 8);

        const float e[4]  = {E.x, E.y, E.z, E.w};
        const float vv[4] = {V.x, V.y, V.z, V.w};
        const float s0[4] = {A.x, A.w, B.z, C.y};
        const float s1[4] = {A.y, B.x, B.w, C.z};
        const float s2[4] = {A.z, B.y, C.x, C.w};
        float xx[4], yy[4], xy[4];
        #pragma unroll
        for (int p = 0; p < 4; ++p) {
            const float v  = vv[p];
            const float fr = e[p] * rcpf(1.f - v * v);
            xx[p] = (s0[p] + v * s1[p]) * fr;
            yy[p] = (v * s0[p] + s1[p]) * fr;
            xy[p] = (s2[p] * (1.f - v) * 0.5f) * fr;
        }
        const int cq = 4 * q;
        *(float4*)&sE [r][cq] = E;
        *(float4*)&sxx[r][cq] = make_float4(xx[0], xx[1], xx[2], xx[3]);
        *(float4*)&syy[r][cq] = make_float4(yy[0], yy[1], yy[2], yy[3]);
        *(float4*)&sxy[r][cq] = make_float4(xy[0], xy[1], xy[2], xy[3]);
        if (r < TILE_H && q < 16)   // exclusive 8x64 interior: each pixel once
            sumE += e[0] + e[1] + e[2] + e[3];
    }
    __syncthreads();

    // ---- stencil: 2 output rows per thread, 3-row sliding window ----
    {
        const int tx = tid & 63;
        const int ty = tid >> 6;
        const int lb = ty * 2;

        // row7: E row-sum, sxx row-sum, sxy row-sum, sxy L/R, syy L/R
        float w0[7], w1[7], w2[7];
        #define ROW7(rr, o) do {                                            \
            o[0] = sE [rr][tx] + sE [rr][tx + 1] + sE [rr][tx + 2];         \
            o[1] = sxx[rr][tx] + sxx[rr][tx + 1] + sxx[rr][tx + 2];         \
            const float l_ = sxy[rr][tx], m_ = sxy[rr][tx + 1],             \
                        g_ = sxy[rr][tx + 2];                               \
            o[2] = l_ + m_ + g_;  o[3] = l_;  o[4] = g_;                    \
            o[5] = syy[rr][tx];   o[6] = syy[rr][tx + 2];                   \
        } while (0)

        ROW7(lb + 0, w0);
        ROW7(lb + 1, w1);

        const bool cok = (c0 + tx) < (WW - 2);
        #pragma unroll
        for (int k = 0; k < 2; ++k) {
            ROW7(lb + k + 2, w2);
            const int go = r0 + lb + k;
            if (cok && go < (HH - 2)) {
                const float rEc = rcpf(w0[0] + w1[0] + w2[0]);
                const float fx = (w2[1] - w0[1])
                               + (w0[3] + w1[3] + w2[3])
                               - (w0[4] + w1[4] + w2[4]);
                const float fy = (w0[5] + w1[5] + w2[5])
                               - (w0[6] + w1[6] + w2[6])
                               + (w2[2] - w0[2]);
                ax += fabsf(fx) * rEc;
                ay += fabsf(fy) * rEc;
            }
            #pragma unroll
            for (int j = 0; j < 7; ++j) { w0[j] = w1[j]; w1[j] = w2[j]; }
        }
        #undef ROW7
    }

    // ---- block reduction -> per-block partials ----
    #pragma unroll
    for (int off = 32; off > 0; off >>= 1) {
        ax   += __shfl_down(ax, off);
        ay   += __shfl_down(ay, off);
        sumE += __shfl_down(sumE, off);
    }
    const int wave = tid >> 6, lane = tid & 63;
    if (lane == 0) { red[0][wave] = ax; red[1][wave] = ay; red[2][wave] = sumE; }
    __syncthreads();
    if (tid == 0) {
        const int b = blockIdx.y * GRIDX + blockIdx.x;
        part[b]               = red[0][0] + red[0][1] + red[0][2] + red[0][3];
        part[NBLOCKS + b]     = red[1][0] + red[1][1] + red[1][2] + red[1][3];
        part[2 * NBLOCKS + b] = red[2][0] + red[2][1] + red[2][2] + red[2][3];
    }
}

__global__ __launch_bounds__(256) void finalize_kernel(
    const float* __restrict__ part, float* __restrict__ out)
{
    const int tid = threadIdx.x;
    const float4* px = (const float4*)(part);
    const float4* py = (const float4*)(part + NBLOCKS);
    const float4* pe = (const float4*)(part + 2 * NBLOCKS);
    float x = 0.f, y = 0.f, e = 0.f;
    #pragma unroll
    for (int k = 0; k < 8; ++k) {          // 2048 float4 per plane / 256 threads
        const int i = tid + k * 256;
        const float4 a = px[i], b = py[i], c = pe[i];
        x += a.x + a.y + a.z + a.w;
        y += b.x + b.y + b.z + b.w;
        e += c.x + c.y + c.z + c.w;
    }
    #pragma unroll
    for (int off = 32; off > 0; off >>= 1) {
        x += __shfl_down(x, off);
        y += __shfl_down(y, off);
        e += __shfl_down(e, off);
    }
    __shared__ float red[3][4];
    const int wave = tid >> 6, lane = tid & 63;
    if (lane == 0) { red[0][wave] = x; red[1][wave] = y; red[2][wave] = e; }
    __syncthreads();
    if (tid == 0) {
        const float rx = red[0][0] + red[0][1] + red[0][2] + red[0][3];
        const float ry = red[1][0] + red[1][1] + red[1][2] + red[1][3];
        const float re = red[2][0] + red[2][1] + red[2][2] + red[2][3];
        const float M = (float)((HH - 2) * (WW - 2));
        const float loss_x = rx / M;
        const float loss_y = ry / M;
        const float loss_e = fabsf(re / (float)(HH * WW) - 1.0f);
        out[0] = loss_x + loss_y + loss_e * 0.01f;
    }
}

extern "C" void kernel_launch(void* const* d_in, const int* in_sizes, int n_in,
                              void* d_out, int out_size, void* d_ws, size_t ws_size,
                              hipStream_t stream) {
    const float* pred_E = (const float*)d_in[0];
    const float* pred_v = (const float*)d_in[1];
    const float* strain = (const float*)d_in[2];
    float* out  = (float*)d_out;
    float* part = (float*)d_ws;   // 3 * 8192 floats = 96 KB

    dim3 grid(GRIDX, GRIDY);      // 32 x 256 = 8192 blocks; 8/CU resident, 4 gens
    fused_loss_kernel<<<grid, 256, 0, stream>>>(pred_E, pred_v, strain, part);
    finalize_kernel<<<1, 256, 0, stream>>>(part, out);
}